// Round 1
// baseline (104.272 us; speedup 1.0000x reference)
//
#include <hip/hip_runtime.h>
#include <hip/hip_bf16.h>
#include <math.h>

// Problem dims (fixed by setup_inputs): B=64 samples, N=512 spins/flips, H=2048 hidden
constexpr int NB = 64;
constexpr int NN = 512;
constexpr int NH = 2048;
constexpr float LN2 = 0.6931471805599453f;

// Workspace layout (in floats)
constexpr size_t OFF_T2  = 0;                      // t2[k][h] = tanh(2W[k][h])         : 512*2048
constexpr size_t OFF_LC  = OFF_T2  + (size_t)NN*NH;   // LC[k] = sum_h lncosh(2W[k][h]) : 512
constexpr size_t OFF_XT  = OFF_LC  + NN;              // xt[n][b] = x[b][n]             : 512*64
constexpr size_t OFF_TT  = OFF_XT  + (size_t)NN*NB;   // Tt[h][b] = tanh(theta[b][h])   : 2048*64
constexpr size_t OFF_THP = OFF_TT  + (size_t)NH*NB;   // thp[nc][b][h] partial GEMM     : 8*64*2048
constexpr size_t OFF_DS  = OFF_THP + (size_t)8*NB*NH; // dsum[k][b] accumulated logs    : 512*64

// ---------------------------------------------------------------- K0: x transpose
__global__ void k_xt(const float* __restrict__ x, float* __restrict__ xt) {
    int t = blockIdx.x * 256 + threadIdx.x;   // 32768 = n*64 + b
    int b = t & 63, n = t >> 6;
    xt[t] = x[b * NN + n];
}

// ------------------------------------------- K1: t2 = tanh(2W), LC[k] = sum lncosh(2W)
__global__ void k_prep_w(const float* __restrict__ W, float* __restrict__ t2,
                         float* __restrict__ LC) {
    int k = blockIdx.x;          // one block per spin row k
    int tid = threadIdx.x;
    float lsum = 0.f;
#pragma unroll
    for (int i = 0; i < 8; i++) {
        int h = tid + i * 256;
        float y  = 2.0f * W[k * NH + h];
        float ay = fabsf(y);
        float e  = __expf(-2.0f * ay);
        float th = (1.0f - e) / (1.0f + e);        // tanh(|y|)
        t2[k * NH + h] = copysignf(th, y);
        lsum += ay + log1pf(e) - LN2;              // lncosh(y), stable
    }
    __shared__ float red[256];
    red[tid] = lsum; __syncthreads();
    for (int s = 128; s > 0; s >>= 1) {
        if (tid < s) red[tid] += red[tid + s];
        __syncthreads();
    }
    if (tid == 0) LC[k] = red[0];
}

// ---------------------- K2: split-K GEMM partials  thp[nc][b][h] = sum_{n in chunk} x[b][n] W[n][h]
__global__ void k_gemm(const float* __restrict__ W, const float* __restrict__ xt,
                       float* __restrict__ thp) {
    int h  = blockIdx.x * 256 + threadIdx.x;   // 8 h-tiles
    int bt = blockIdx.y;                       // 4 b-tiles of 16
    int nc = blockIdx.z;                       // 8 n-chunks of 64
    float acc[16];
#pragma unroll
    for (int j = 0; j < 16; j++) acc[j] = 0.f;
    const float* xp = xt + (size_t)nc * 64 * NB + bt * 16;  // uniform -> s_load
    const float* wp = W + (size_t)nc * 64 * NH + h;
    for (int n = 0; n < 64; n++) {
        float w = wp[(size_t)n * NH];
#pragma unroll
        for (int j = 0; j < 16; j++) acc[j] = fmaf(xp[n * NB + j], w, acc[j]);
    }
    float* op = thp + (size_t)nc * NB * NH + (size_t)(bt * 16) * NH + h;
#pragma unroll
    for (int j = 0; j < 16; j++) op[(size_t)j * NH] = acc[j];
}

// --------------------------- K3: theta = bias + sum partials; Tt[h][b] = tanh(theta)
__global__ void k_tanh_t(const float* __restrict__ thp, const float* __restrict__ bvec,
                         float* __restrict__ Tt) {
    int g = blockIdx.x * 256 + threadIdx.x;   // 131072
    int h = g & (NH - 1), b = g >> 11;
    float th = bvec[h];
#pragma unroll
    for (int nc = 0; nc < 8; nc++) th += thp[(size_t)nc * NB * NH + (size_t)b * NH + h];
    float ay = fabsf(th);
    float e  = __expf(-2.0f * ay);
    float t  = (1.0f - e) / (1.0f + e);
    Tt[h * NB + b] = copysignf(t, th);
}

// ------------------- K4: main flip kernel. lane<->b, wave covers 2 k's, block = 8 k's x 256 h
__global__ __launch_bounds__(256) void k_main(const float* __restrict__ t2,
                                              const float* __restrict__ Tt,
                                              const float* __restrict__ xt,
                                              float* __restrict__ dsum) {
    __shared__ float Tl[256 * NB];            // 64 KB slab: T[h0..h0+256)[all b]
    int tid = threadIdx.x;
    int kt  = blockIdx.x;                     // 64 k-tiles of 8
    int hc  = blockIdx.y;                     // 8 h-chunks of 256
    // stage T slab (contiguous in Tt since layout is [h][b])
    const float4* src = (const float4*)(Tt + (size_t)hc * 256 * NB);
    float4* dst = (float4*)Tl;
#pragma unroll
    for (int i = 0; i < 16; i++) dst[tid + i * 256] = src[tid + i * 256];
    __syncthreads();

    int wave = tid >> 6, lane = tid & 63;
    int k0 = __builtin_amdgcn_readfirstlane(kt * 8 + wave * 2);  // force SGPR -> s_load t2 rows
    float ms0 = -xt[k0 * NB + lane];          // -x[b][k0]
    float ms1 = -xt[(k0 + 1) * NB + lane];
    const float* r0 = t2 + (size_t)k0 * NH + hc * 256;
    const float* r1 = r0 + NH;

    float lp0 = 0.f, lp1 = 0.f;
    for (int h0 = 0; h0 < 256; h0 += 32) {
        float p0 = 1.f, p1 = 1.f;
#pragma unroll 8
        for (int hh = 0; hh < 32; hh++) {
            int h = h0 + hh;
            float T = Tl[h * NB + lane];      // stride-1 over lanes: conflict-free
            p0 *= fmaf(r0[h] * T, ms0, 1.0f); // u = 1 - s*T*tanh(2W)
            p1 *= fmaf(r1[h] * T, ms1, 1.0f);
        }
        lp0 += __logf(p0);                    // |ln u| <= 2|W|max ~ 0.1 -> chunk product safe
        lp1 += __logf(p1);
    }
    atomicAdd(&dsum[k0 * NB + lane], lp0);
    atomicAdd(&dsum[(k0 + 1) * NB + lane], lp1);
}

// ----------------------------- K5: out[b] = sum_k Oxy[k] * exp(dsum + LC[k] - 2 s a[k])
__global__ void k_out(const float* __restrict__ dsum, const float* __restrict__ LC,
                      const float* __restrict__ xt, const float* __restrict__ a,
                      const float* __restrict__ Oxy, float* __restrict__ out) {
    int b = blockIdx.x, tid = threadIdx.x;
    float sum = 0.f;
    for (int k = tid; k < NN; k += 256) {
        float s = xt[k * NB + b];
        float d = dsum[k * NB + b] + LC[k] - 2.0f * s * a[k];
        sum += Oxy[k] * __expf(d);
    }
    __shared__ float red[256];
    red[tid] = sum; __syncthreads();
    for (int st = 128; st > 0; st >>= 1) {
        if (tid < st) red[tid] += red[tid + st];
        __syncthreads();
    }
    if (tid == 0) out[b] = red[0];
}

extern "C" void kernel_launch(void* const* d_in, const int* in_sizes, int n_in,
                              void* d_out, int out_size, void* d_ws, size_t ws_size,
                              hipStream_t stream) {
    const float* x    = (const float*)d_in[0];
    const float* W    = (const float*)d_in[1];
    const float* bvec = (const float*)d_in[2];
    const float* a    = (const float*)d_in[3];
    const float* Oxy  = (const float*)d_in[4];
    float* out = (float*)d_out;

    float* ws   = (float*)d_ws;
    float* t2   = ws + OFF_T2;
    float* LC   = ws + OFF_LC;
    float* xt   = ws + OFF_XT;
    float* Tt   = ws + OFF_TT;
    float* thp  = ws + OFF_THP;
    float* dsum = ws + OFF_DS;

    k_xt<<<NN * NB / 256, 256, 0, stream>>>(x, xt);
    k_prep_w<<<NN, 256, 0, stream>>>(W, t2, LC);
    k_gemm<<<dim3(NH / 256, NB / 16, 8), 256, 0, stream>>>(W, xt, thp);
    k_tanh_t<<<NB * NH / 256, 256, 0, stream>>>(thp, bvec, Tt);
    hipMemsetAsync(dsum, 0, (size_t)NN * NB * sizeof(float), stream);
    k_main<<<dim3(NN / 8, NH / 256), 256, 0, stream>>>(t2, Tt, xt, dsum);
    k_out<<<NB, 256, 0, stream>>>(dsum, LC, xt, a, Oxy, out);
}